// Round 2
// baseline (2111.973 us; speedup 1.0000x reference)
//
#include <hip/hip_runtime.h>

// ---------------------------------------------------------------------------
// MPN (chemprop) on MI355X. bf16 MFMA (16x16x32), fp32 accum.
//   relu(inp + m@W_h) == relu([f_bonds | m] @ [W_i ; W_h])  -> no stored inp.
//   combine (a_msg[b2a[b]] - msg[b2revb[b]]) fused into GEMM A-operand.
// Workspace (~367 MiB):
//   wih  [320][480] bf16   stacked [W_i;W_h]^T (n-major, k-contig)
//   wto  [320][448] bf16   W_o^T (k: 0..299 msg, 304..436 atom)
//   fbp  [200000][160] bf16  f_bonds padded
//   amsg [100000][320] bf16
//   msgA [200000][320] bf16   (reused as concat [100000][448] after loop)
//   msgB [200000][320] bf16   (reused as hid [100000][300] fp32 at the end)
// ---------------------------------------------------------------------------

#define DEVFN static __device__ __forceinline__

typedef __attribute__((ext_vector_type(8))) __bf16 bf16x8;
typedef __attribute__((ext_vector_type(4))) float floatx4;

DEVFN unsigned short f2bf(float f) {
    unsigned int u = __float_as_uint(f);
    u += 0x7FFFu + ((u >> 16) & 1u);   // RNE
    return (unsigned short)(u >> 16);
}
DEVFN float bf2f(unsigned int u) { return __uint_as_float(u << 16); }

// ---------------------------------------------------------------------------
__global__ __launch_bounds__(256) void dbg_fill(float* out, int n, float v) {
    int t = blockIdx.x * 256 + threadIdx.x;
    if (t < n) out[t] = v;
}

// Wih[320][480]: k<147 -> W_i[k][n]; 160<=k<460 -> W_h[k-160][n]; else 0
__global__ __launch_bounds__(256) void prep_wih(const float* __restrict__ Wi,
                                                const float* __restrict__ Wh,
                                                unsigned short* __restrict__ Wt) {
    int t = blockIdx.x * 256 + threadIdx.x;       // 320*480
    if (t >= 320 * 480) return;
    int n = t / 480, k = t - n * 480;
    float v = 0.f;
    if (n < 300) {
        if (k < 147) v = Wi[k * 300 + n];
        else if (k >= 160 && k < 460) v = Wh[(k - 160) * 300 + n];
    }
    Wt[t] = f2bf(v);
}

// Wto[320][448]: k<300 -> W_o[133+k][n]; 304<=k<437 -> W_o[k-304][n]; else 0
__global__ __launch_bounds__(256) void prep_wto(const float* __restrict__ Wo,
                                                unsigned short* __restrict__ Wt) {
    int t = blockIdx.x * 256 + threadIdx.x;       // 320*448
    if (t >= 320 * 448) return;
    int n = t / 448, k = t - n * 448;
    float v = 0.f;
    if (n < 300) {
        if (k < 300) v = Wo[(133 + k) * 300 + n];
        else if (k >= 304 && k < 437) v = Wo[(k - 304) * 300 + n];
    }
    Wt[t] = f2bf(v);
}

// f_bonds [200000][147] fp32 -> [200000][160] bf16 padded
__global__ __launch_bounds__(256) void pad_bonds(const float* __restrict__ fb,
                                                 unsigned short* __restrict__ out) {
    int t = blockIdx.x * 256 + threadIdx.x;       // (bond, chunk of 8 cols)
    if (t >= 200000 * 20) return;
    int b = t / 20, c = t - b * 20;
    unsigned int o[4];
#pragma unroll
    for (int p = 0; p < 4; ++p) {
        int sc = c * 8 + p * 2;
        float v0 = (sc < 147) ? fb[(size_t)b * 147 + sc] : 0.f;
        float v1 = (sc + 1 < 147) ? fb[(size_t)b * 147 + sc + 1] : 0.f;
        o[p] = (unsigned int)f2bf(v0) | ((unsigned int)f2bf(v1) << 16);
    }
    *(uint4*)(out + (size_t)b * 160 + c * 8) = make_uint4(o[0], o[1], o[2], o[3]);
}

// f_atoms [100000][133] fp32 -> concat cols 304..447 (133 real + zero pad)
__global__ __launch_bounds__(256) void atoms_concat(const float* __restrict__ fa,
                                                    unsigned short* __restrict__ concat) {
    int t = blockIdx.x * 256 + threadIdx.x;       // (atom, chunk of 8)
    if (t >= 100000 * 18) return;
    int a = t / 18, c = t - a * 18;
    unsigned int o[4];
#pragma unroll
    for (int p = 0; p < 4; ++p) {
        int sc = c * 8 + p * 2;
        float v0 = (sc < 133) ? fa[(size_t)a * 133 + sc] : 0.f;
        float v1 = (sc + 1 < 133) ? fa[(size_t)a * 133 + sc + 1] : 0.f;
        o[p] = (unsigned int)f2bf(v0) | ((unsigned int)f2bf(v1) << 16);
    }
    *(uint4*)(concat + (size_t)a * 448 + 304 + c * 8) = make_uint4(o[0], o[1], o[2], o[3]);
}

// a_msg[a] = sum_j msg[a2b[a][j]]   (bf16 in, fp32 accum, bf16 out)
template <int CH>
__global__ __launch_bounds__(256) void gather_sum(const unsigned short* __restrict__ msg,
                                                  const int* __restrict__ a2b,
                                                  unsigned short* __restrict__ out,
                                                  int ostride, int nA) {
    int t = blockIdx.x * 256 + threadIdx.x;
    if (t >= nA * CH) return;
    int a = t / CH, c = t - a * CH;
    float s[8] = {0, 0, 0, 0, 0, 0, 0, 0};
#pragma unroll
    for (int j = 0; j < 6; ++j) {
        int b = a2b[a * 6 + j];
        uint4 v = *(const uint4*)(msg + (size_t)b * 320 + c * 8);
        s[0] += bf2f(v.x & 0xffffu); s[1] += bf2f(v.x >> 16);
        s[2] += bf2f(v.y & 0xffffu); s[3] += bf2f(v.y >> 16);
        s[4] += bf2f(v.z & 0xffffu); s[5] += bf2f(v.z >> 16);
        s[6] += bf2f(v.w & 0xffffu); s[7] += bf2f(v.w >> 16);
    }
    unsigned int o[4];
#pragma unroll
    for (int p = 0; p < 4; ++p)
        o[p] = (unsigned int)f2bf(s[2 * p]) | ((unsigned int)f2bf(s[2 * p + 1]) << 16);
    *(uint4*)(out + (size_t)a * ostride + c * 8) = make_uint4(o[0], o[1], o[2], o[3]);
}

// ---------------------------------------------------------------------------
// GEMM: C[M][NT*16] = [A0 | A1] @ Wt^T, Wt[NT*16][BSTRIDE] k-contig.
//   A0: KT0 k-tiles from A0 (row stride a0stride)
//   A1 (MODE 1 only): KT1 k-tiles built as bf(amsg[b2a[r]] - msg[b2revb[r]])
// MODE 0/1: outp[r*320+col] = relu(acc) bf16
// MODE 2:   hid[r*300+col]  = relu(acc + bo[col]) fp32, col<300, r<M
// Block = 4 waves x 16 rows = 64 rows; each wave does all NT n-tiles.
// ---------------------------------------------------------------------------
template <int KT0, int KT1, int NT, int MODE, int BSTRIDE>
__global__ __launch_bounds__(256) void gemm_k(const unsigned short* __restrict__ A0,
                                              int a0stride,
                                              const unsigned short* __restrict__ amsg,
                                              const unsigned short* __restrict__ msg,
                                              const int* __restrict__ b2a,
                                              const int* __restrict__ b2revb,
                                              const unsigned short* __restrict__ Wt,
                                              unsigned short* __restrict__ outp,
                                              float* __restrict__ hid,
                                              const float* __restrict__ bo, int M) {
    constexpr int N = NT * 16;
    const int lane = threadIdx.x & 63;
    const int wave = threadIdx.x >> 6;
    const int quad = lane >> 4;
    const int l16 = lane & 15;
    const int m0 = blockIdx.x * 64 + wave * 16;
    int row = m0 + l16;
    if (row > M - 1) row = M - 1;                  // clamp tail (MODE 2 only)
    const unsigned short* a0p = A0 + (size_t)row * a0stride + quad * 8;
    const unsigned short* Bp = Wt + (size_t)l16 * BSTRIDE + quad * 8;

    const unsigned short* a1p = nullptr;
    const unsigned short* m1p = nullptr;
    if (MODE == 1) {
        int ra = b2a[row], rb = b2revb[row];
        a1p = amsg + (size_t)ra * 320 + quad * 8;
        m1p = msg + (size_t)rb * 320 + quad * 8;
    }

    floatx4 acc[NT];
#pragma unroll
    for (int nt = 0; nt < NT; ++nt) acc[nt] = (floatx4){0.f, 0.f, 0.f, 0.f};

#pragma unroll
    for (int kt = 0; kt < KT0 + KT1; ++kt) {
        bf16x8 a;
        if (kt < KT0) {
            a = *(const bf16x8*)(a0p + kt * 32);
        } else {
            uint4 va = *(const uint4*)(a1p + (kt - KT0) * 32);
            uint4 vm = *(const uint4*)(m1p + (kt - KT0) * 32);
            unsigned int ax[4] = {va.x, va.y, va.z, va.w};
            unsigned int mx[4] = {vm.x, vm.y, vm.z, vm.w};
            unsigned int o[4];
#pragma unroll
            for (int p = 0; p < 4; ++p) {
                float lo = bf2f(ax[p] & 0xffffu) - bf2f(mx[p] & 0xffffu);
                float hi = bf2f(ax[p] >> 16) - bf2f(mx[p] >> 16);
                o[p] = (unsigned int)f2bf(lo) | ((unsigned int)f2bf(hi) << 16);
            }
            a = __builtin_bit_cast(bf16x8, make_uint4(o[0], o[1], o[2], o[3]));
        }
#pragma unroll
        for (int nt = 0; nt < NT; ++nt) {
            bf16x8 b = *(const bf16x8*)(Bp + (size_t)nt * 16 * BSTRIDE + kt * 32);
            acc[nt] = __builtin_amdgcn_mfma_f32_16x16x32_bf16(a, b, acc[nt], 0, 0, 0);
        }
    }

    const int orow = m0 + quad * 4;
#pragma unroll
    for (int nt = 0; nt < NT; ++nt) {
        const int col = nt * 16 + l16;
#pragma unroll
        for (int i = 0; i < 4; ++i) {
            int r = orow + i;
            float c = acc[nt][i];
            if (MODE == 2) {
                if (col < 300 && r < M)
                    hid[(size_t)r * 300 + col] = fmaxf(c + bo[col], 0.f);
            } else {
                outp[(size_t)r * N + col] = f2bf(fmaxf(c, 0.f));
            }
        }
    }
}

// ---------------------------------------------------------------------------
// Per-molecule mean. mol_ids sorted -> binary search row range. No atomics.
// ---------------------------------------------------------------------------
__global__ __launch_bounds__(320) void mean_k(const float* __restrict__ hid,
                                              const int* __restrict__ mol_ids,
                                              float* __restrict__ out, int nA) {
    int mol = blockIdx.x;
    int lo, hi;
    {
        int l = 0, h = nA;
        while (l < h) { int m = (l + h) >> 1; if (mol_ids[m] < mol) l = m + 1; else h = m; }
        lo = l;
    }
    {
        int l = lo, h = nA;
        while (l < h) { int m = (l + h) >> 1; if (mol_ids[m] < mol + 1) l = m + 1; else h = m; }
        hi = l;
    }
    int col = threadIdx.x;
    if (col >= 300) return;
    float s = 0.f;
    for (int a = lo; a < hi; ++a) s += hid[(size_t)a * 300 + col];
    int cnt = hi - lo;
    out[(size_t)mol * 300 + col] = s / (float)(cnt > 0 ? cnt : 1);
}

// ---------------------------------------------------------------------------
extern "C" void kernel_launch(void* const* d_in, const int* in_sizes, int n_in,
                              void* d_out, int out_size, void* d_ws, size_t ws_size,
                              hipStream_t stream) {
    (void)in_sizes; (void)n_in;
    const float* f_atoms = (const float*)d_in[0];
    const float* f_bonds = (const float*)d_in[1];
    const float* W_i     = (const float*)d_in[2];
    const float* W_h     = (const float*)d_in[3];
    const float* W_o     = (const float*)d_in[4];
    const float* b_o     = (const float*)d_in[5];
    const int*   a2b     = (const int*)d_in[6];
    const int*   b2a     = (const int*)d_in[7];
    const int*   b2revb  = (const int*)d_in[8];
    const int*   mol_ids = (const int*)d_in[9];

    const size_t sz_wih  = 320ull * 480 * 2;           // 307,200
    const size_t sz_wto  = 320ull * 448 * 2;           // 286,720
    const size_t sz_fbp  = 200000ull * 160 * 2;        // 64,000,000
    const size_t sz_amsg = 100000ull * 320 * 2;        // 64,000,000
    const size_t sz_msg  = 200000ull * 320 * 2;        // 128,000,000
    const size_t need = sz_wih + sz_wto + sz_fbp + sz_amsg + 2 * sz_msg; // ~367 MiB

    if (ws_size < need) {
        // Debug channel: absmax will report ws_size in MiB.
        dbg_fill<<<(out_size + 255) / 256, 256, 0, stream>>>(
            (float*)d_out, out_size, (float)(ws_size >> 20));
        return;
    }

    char* ws = (char*)d_ws;
    unsigned short* wih  = (unsigned short*)(ws);
    unsigned short* wto  = (unsigned short*)(ws + sz_wih);
    unsigned short* fbp  = (unsigned short*)(ws + sz_wih + sz_wto);
    unsigned short* amsg = (unsigned short*)(ws + sz_wih + sz_wto + sz_fbp);
    unsigned short* msgA = (unsigned short*)(ws + sz_wih + sz_wto + sz_fbp + sz_amsg);
    unsigned short* msgB = (unsigned short*)(ws + sz_wih + sz_wto + sz_fbp + sz_amsg + sz_msg);
    unsigned short* concat = msgA;                     // msgA dead after loop
    float*          hid    = (float*)msgB;             // msgB dead after final gather

    prep_wih<<<600, 256, 0, stream>>>(W_i, W_h, wih);
    prep_wto<<<560, 256, 0, stream>>>(W_o, wto);
    pad_bonds<<<15625, 256, 0, stream>>>(f_bonds, fbp);

    // msgA = relu(f_bonds @ W_i)   (K = 160 head of wih rows)
    gemm_k<5, 0, 20, 0, 480><<<3125, 256, 0, stream>>>(
        fbp, 160, nullptr, nullptr, nullptr, nullptr, wih, msgA, nullptr, nullptr, 200000);

    unsigned short* cur = msgA;
    unsigned short* other = msgB;
    for (int d = 0; d < 3; ++d) {   // DEPTH-1
        gather_sum<40><<<15625, 256, 0, stream>>>(cur, a2b, amsg, 320, 100000);
        // other = relu([fbp | amsg[b2a]-cur[b2revb]] @ [W_i;W_h])
        gemm_k<5, 10, 20, 1, 480><<<3125, 256, 0, stream>>>(
            fbp, 160, amsg, cur, b2a, b2revb, wih, other, nullptr, nullptr, 200000);
        unsigned short* t = cur; cur = other; other = t;
    }

    // final gather into concat cols 0..303 (cur == msgB here; concat == msgA)
    gather_sum<38><<<14844, 256, 0, stream>>>(cur, a2b, concat, 448, 100000);
    atoms_concat<<<7032, 256, 0, stream>>>(f_atoms, concat);
    // hid = relu(concat @ W_o + b_o)
    gemm_k<14, 0, 20, 2, 448><<<1563, 256, 0, stream>>>(
        concat, 448, nullptr, nullptr, nullptr, nullptr, wto, nullptr, hid, b_o, 100000);
    // per-mol mean
    mean_k<<<8192, 320, 0, stream>>>(hid, mol_ids, (float*)d_out, 100000);
}

// Round 3
// 1236.667 us; speedup vs baseline: 1.7078x; 1.7078x over previous
//
#include <hip/hip_runtime.h>

// ---------------------------------------------------------------------------
// MPN (chemprop) on MI355X. bf16 MFMA (16x16x32), fp32 accum.
//   relu(inp + m@W_h) == relu([f_bonds | m] @ [W_i ; W_h])  -> no stored inp.
//   combine (a_msg[b2a[b]] - msg[b2revb[b]]) fused into GEMM A-staging.
// GEMM: LDS double-buffered, block tile 128M x 160N, wave tile 64x80 (4x5).
// Workspace (~367 MiB): wih | wto | fbp | amsg | msgA | msgB
// ---------------------------------------------------------------------------

#define DEVFN static __device__ __forceinline__

typedef __attribute__((ext_vector_type(8))) __bf16 bf16x8;
typedef __attribute__((ext_vector_type(4))) float floatx4;

DEVFN unsigned short f2bf(float f) {
    unsigned int u = __float_as_uint(f);
    u += 0x7FFFu + ((u >> 16) & 1u);   // RNE
    return (unsigned short)(u >> 16);
}
DEVFN float bf2f(unsigned int u) { return __uint_as_float(u << 16); }

// packed bf16x2 subtract via fp32 (exact in fp32, RNE back)
DEVFN unsigned int bfsub2(unsigned int a, unsigned int m) {
    float lo = bf2f(a & 0xffffu) - bf2f(m & 0xffffu);
    float hi = bf2f(a >> 16) - bf2f(m >> 16);
    return (unsigned int)f2bf(lo) | ((unsigned int)f2bf(hi) << 16);
}
DEVFN uint4 bfsub8(uint4 a, uint4 m) {
    return make_uint4(bfsub2(a.x, m.x), bfsub2(a.y, m.y),
                      bfsub2(a.z, m.z), bfsub2(a.w, m.w));
}

// ---------------------------------------------------------------------------
__global__ __launch_bounds__(256) void dbg_fill(float* out, int n, float v) {
    int t = blockIdx.x * 256 + threadIdx.x;
    if (t < n) out[t] = v;
}

// Wih[320][480]: k<147 -> W_i[k][n]; 160<=k<460 -> W_h[k-160][n]; else 0
__global__ __launch_bounds__(256) void prep_wih(const float* __restrict__ Wi,
                                                const float* __restrict__ Wh,
                                                unsigned short* __restrict__ Wt) {
    int t = blockIdx.x * 256 + threadIdx.x;
    if (t >= 320 * 480) return;
    int n = t / 480, k = t - n * 480;
    float v = 0.f;
    if (n < 300) {
        if (k < 147) v = Wi[k * 300 + n];
        else if (k >= 160 && k < 460) v = Wh[(k - 160) * 300 + n];
    }
    Wt[t] = f2bf(v);
}

// Wto[320][448]: k<300 -> W_o[133+k][n]; 304<=k<437 -> W_o[k-304][n]; else 0
__global__ __launch_bounds__(256) void prep_wto(const float* __restrict__ Wo,
                                                unsigned short* __restrict__ Wt) {
    int t = blockIdx.x * 256 + threadIdx.x;
    if (t >= 320 * 448) return;
    int n = t / 448, k = t - n * 448;
    float v = 0.f;
    if (n < 300) {
        if (k < 300) v = Wo[(133 + k) * 300 + n];
        else if (k >= 304 && k < 437) v = Wo[(k - 304) * 300 + n];
    }
    Wt[t] = f2bf(v);
}

// f_bonds [200000][147] fp32 -> [200000][160] bf16 padded
__global__ __launch_bounds__(256) void pad_bonds(const float* __restrict__ fb,
                                                 unsigned short* __restrict__ out) {
    int t = blockIdx.x * 256 + threadIdx.x;
    if (t >= 200000 * 20) return;
    int b = t / 20, c = t - b * 20;
    unsigned int o[4];
#pragma unroll
    for (int p = 0; p < 4; ++p) {
        int sc = c * 8 + p * 2;
        float v0 = (sc < 147) ? fb[(size_t)b * 147 + sc] : 0.f;
        float v1 = (sc + 1 < 147) ? fb[(size_t)b * 147 + sc + 1] : 0.f;
        o[p] = (unsigned int)f2bf(v0) | ((unsigned int)f2bf(v1) << 16);
    }
    *(uint4*)(out + (size_t)b * 160 + c * 8) = make_uint4(o[0], o[1], o[2], o[3]);
}

// f_atoms [100000][133] fp32 -> concat cols 304..447
__global__ __launch_bounds__(256) void atoms_concat(const float* __restrict__ fa,
                                                    unsigned short* __restrict__ concat) {
    int t = blockIdx.x * 256 + threadIdx.x;
    if (t >= 100000 * 18) return;
    int a = t / 18, c = t - a * 18;
    unsigned int o[4];
#pragma unroll
    for (int p = 0; p < 4; ++p) {
        int sc = c * 8 + p * 2;
        float v0 = (sc < 133) ? fa[(size_t)a * 133 + sc] : 0.f;
        float v1 = (sc + 1 < 133) ? fa[(size_t)a * 133 + sc + 1] : 0.f;
        o[p] = (unsigned int)f2bf(v0) | ((unsigned int)f2bf(v1) << 16);
    }
    *(uint4*)(concat + (size_t)a * 448 + 304 + c * 8) = make_uint4(o[0], o[1], o[2], o[3]);
}

// a_msg[a] = sum_j msg[a2b[a][j]]
template <int CH>
__global__ __launch_bounds__(256) void gather_sum(const unsigned short* __restrict__ msg,
                                                  const int* __restrict__ a2b,
                                                  unsigned short* __restrict__ out,
                                                  int ostride, int nA) {
    int t = blockIdx.x * 256 + threadIdx.x;
    if (t >= nA * CH) return;
    int a = t / CH, c = t - a * CH;
    float s[8] = {0, 0, 0, 0, 0, 0, 0, 0};
#pragma unroll
    for (int j = 0; j < 6; ++j) {
        int b = a2b[a * 6 + j];
        uint4 v = *(const uint4*)(msg + (size_t)b * 320 + c * 8);
        s[0] += bf2f(v.x & 0xffffu); s[1] += bf2f(v.x >> 16);
        s[2] += bf2f(v.y & 0xffffu); s[3] += bf2f(v.y >> 16);
        s[4] += bf2f(v.z & 0xffffu); s[5] += bf2f(v.z >> 16);
        s[6] += bf2f(v.w & 0xffffu); s[7] += bf2f(v.w >> 16);
    }
    unsigned int o[4];
#pragma unroll
    for (int p = 0; p < 4; ++p)
        o[p] = (unsigned int)f2bf(s[2 * p]) | ((unsigned int)f2bf(s[2 * p + 1]) << 16);
    *(uint4*)(out + (size_t)a * ostride + c * 8) = make_uint4(o[0], o[1], o[2], o[3]);
}

// ---------------------------------------------------------------------------
// LDS-staged GEMM.  C[M][320] = [A0 | combine] @ Wt^T
//   Wt[320][BSTRIDE] k-contiguous rows (weight columns).
//   Block: 128M (grid.x) x 160N (grid.y in {0,1}); 4 waves 2x2; wave 64x80.
//   K = (KT0+KT1)*32. kt<KT0: A from A0 (stride a0s). kt>=KT0 (hidden only):
//   A row r = bf16(amsg[b2a[r]] - msg[b2revb[r]]).
// MODE 0: outp[r*320+col] = relu(acc) bf16
// MODE 2: hid[r*300+col]  = relu(acc + bo[col]) fp32  (col<300)
// LDS: As 2x[128][40] bf16 (pad->2-way, free), Bs 2x[160][32] bf16 with XOR
//      k-quarter swizzle (unit q stored at q^(n&3)) -> 2-way, free.
// ---------------------------------------------------------------------------
template <int KT0, int KT1, int MODE, int BSTRIDE>
__global__ __launch_bounds__(256) void gemm_k(const unsigned short* __restrict__ A0,
                                              int a0s,
                                              const unsigned short* __restrict__ amsg,
                                              const unsigned short* __restrict__ msg,
                                              const int* __restrict__ b2a,
                                              const int* __restrict__ b2revb,
                                              const unsigned short* __restrict__ Wt,
                                              unsigned short* __restrict__ outp,
                                              float* __restrict__ hid,
                                              const float* __restrict__ bo, int M) {
    constexpr int KT = KT0 + KT1;
    __shared__ unsigned short As[2 * 5120];   // [buf][128][40]
    __shared__ unsigned short Bs[2 * 5120];   // [buf][160][32] swizzled

    const int tid = threadIdx.x;
    const int lane = tid & 63;
    const int wave = tid >> 6;
    const int wm = wave & 1, wn = wave >> 1;
    const int l16 = lane & 15, quad = lane >> 4;
    const int m0 = blockIdx.x * 128;
    const int n0 = blockIdx.y * 160;

    // ---- staging setup: A (2 threads/row), B (2.5 16B-units/thread) ----
    const int arow = tid >> 1, ahalf = tid & 1;
    const int gr = min(m0 + arow, M - 1);
    const unsigned short* a0p = A0 + (size_t)gr * a0s + ahalf * 16;
    const unsigned short* a1p = nullptr;
    const unsigned short* m1p = nullptr;
    if (KT1 > 0) {
        a1p = amsg + (size_t)b2a[gr] * 320 + ahalf * 16;
        m1p = msg + (size_t)b2revb[gr] * 320 + ahalf * 16;
    }
    const int u0 = tid, u1 = tid + 256, u2 = tid + 512;
    const unsigned short* bg0 = Wt + (size_t)(n0 + (u0 >> 2)) * BSTRIDE + ((u0 ^ (u0 >> 2)) & 3) * 8;
    const unsigned short* bg1 = Wt + (size_t)(n0 + (u1 >> 2)) * BSTRIDE + ((u1 ^ (u1 >> 2)) & 3) * 8;
    const unsigned short* bg2 = (tid < 128)
        ? Wt + (size_t)(n0 + (u2 >> 2)) * BSTRIDE + ((u2 ^ (u2 >> 2)) & 3) * 8 : Wt;

    // ---- fragment LDS offsets (shorts) ----
    int aoff[4], boff[5];
#pragma unroll
    for (int tm = 0; tm < 4; ++tm)
        aoff[tm] = (wm * 64 + tm * 16 + l16) * 40 + quad * 8;
#pragma unroll
    for (int tn = 0; tn < 5; ++tn) {
        int nl = wn * 80 + tn * 16 + l16;
        boff[tn] = nl * 32 + ((quad ^ nl) & 3) * 8;
    }

    floatx4 acc[4][5];
#pragma unroll
    for (int tm = 0; tm < 4; ++tm)
#pragma unroll
        for (int tn = 0; tn < 5; ++tn) acc[tm][tn] = (floatx4){0.f, 0.f, 0.f, 0.f};

    uint4 ar0, ar1, br0, br1, br2;
    auto ldG = [&](int kt) {
        if (kt < KT0) {
            ar0 = *(const uint4*)(a0p + kt * 32);
            ar1 = *(const uint4*)(a0p + kt * 32 + 8);
        } else {
            int ko = (kt - KT0) * 32;
            uint4 va0 = *(const uint4*)(a1p + ko);
            uint4 va1 = *(const uint4*)(a1p + ko + 8);
            uint4 vm0 = *(const uint4*)(m1p + ko);
            uint4 vm1 = *(const uint4*)(m1p + ko + 8);
            ar0 = bfsub8(va0, vm0);
            ar1 = bfsub8(va1, vm1);
        }
        br0 = *(const uint4*)(bg0 + kt * 32);
        br1 = *(const uint4*)(bg1 + kt * 32);
        if (tid < 128) br2 = *(const uint4*)(bg2 + kt * 32);
    };
    auto stW = [&](int buf) {
        unsigned short* ab = As + buf * 5120 + arow * 40 + ahalf * 16;
        *(uint4*)(ab) = ar0;
        *(uint4*)(ab + 8) = ar1;
        unsigned short* bb = Bs + buf * 5120;
        *(uint4*)(bb + u0 * 8) = br0;
        *(uint4*)(bb + u1 * 8) = br1;
        if (tid < 128) *(uint4*)(bb + u2 * 8) = br2;
    };

    ldG(0);
    stW(0);
    __syncthreads();

#pragma unroll
    for (int kt = 0; kt < KT; ++kt) {
        const int buf = kt & 1;
        if (kt + 1 < KT) ldG(kt + 1);

        bf16x8 av[4], bv[5];
#pragma unroll
        for (int tm = 0; tm < 4; ++tm)
            av[tm] = *(const bf16x8*)(As + buf * 5120 + aoff[tm]);
#pragma unroll
        for (int tn = 0; tn < 5; ++tn)
            bv[tn] = *(const bf16x8*)(Bs + buf * 5120 + boff[tn]);
#pragma unroll
        for (int tn = 0; tn < 5; ++tn)
#pragma unroll
            for (int tm = 0; tm < 4; ++tm)
                acc[tm][tn] = __builtin_amdgcn_mfma_f32_16x16x32_bf16(av[tm], bv[tn], acc[tm][tn], 0, 0, 0);

        if (kt + 1 < KT) stW(buf ^ 1);
        __syncthreads();
    }

    // ---- epilogue ----
    float bias[5];
    if (MODE == 2) {
#pragma unroll
        for (int tn = 0; tn < 5; ++tn) {
            int col = n0 + wn * 80 + tn * 16 + l16;
            bias[tn] = (col < 300) ? bo[col] : 0.f;
        }
    }
#pragma unroll
    for (int tm = 0; tm < 4; ++tm) {
        const int r0 = m0 + wm * 64 + tm * 16 + quad * 4;
#pragma unroll
        for (int tn = 0; tn < 5; ++tn) {
            const int col = n0 + wn * 80 + tn * 16 + l16;
#pragma unroll
            for (int i = 0; i < 4; ++i) {
                int r = r0 + i;
                if (r >= M) continue;
                float c = acc[tm][tn][i];
                if (MODE == 2) {
                    if (col < 300) hid[(size_t)r * 300 + col] = fmaxf(c + bias[tn], 0.f);
                } else {
                    outp[(size_t)r * 320 + col] = f2bf(fmaxf(c, 0.f));
                }
            }
        }
    }
}

// ---------------------------------------------------------------------------
// Per-molecule mean. mol_ids sorted -> binary search row range.
// ---------------------------------------------------------------------------
__global__ __launch_bounds__(320) void mean_k(const float* __restrict__ hid,
                                              const int* __restrict__ mol_ids,
                                              float* __restrict__ out, int nA) {
    int mol = blockIdx.x;
    int lo, hi;
    {
        int l = 0, h = nA;
        while (l < h) { int m = (l + h) >> 1; if (mol_ids[m] < mol) l = m + 1; else h = m; }
        lo = l;
    }
    {
        int l = lo, h = nA;
        while (l < h) { int m = (l + h) >> 1; if (mol_ids[m] < mol + 1) l = m + 1; else h = m; }
        hi = l;
    }
    int col = threadIdx.x;
    if (col >= 300) return;
    float s = 0.f;
    for (int a = lo; a < hi; ++a) s += hid[(size_t)a * 300 + col];
    int cnt = hi - lo;
    out[(size_t)mol * 300 + col] = s / (float)(cnt > 0 ? cnt : 1);
}

// ---------------------------------------------------------------------------
extern "C" void kernel_launch(void* const* d_in, const int* in_sizes, int n_in,
                              void* d_out, int out_size, void* d_ws, size_t ws_size,
                              hipStream_t stream) {
    (void)in_sizes; (void)n_in;
    const float* f_atoms = (const float*)d_in[0];
    const float* f_bonds = (const float*)d_in[1];
    const float* W_i     = (const float*)d_in[2];
    const float* W_h     = (const float*)d_in[3];
    const float* W_o     = (const float*)d_in[4];
    const float* b_o     = (const float*)d_in[5];
    const int*   a2b     = (const int*)d_in[6];
    const int*   b2a     = (const int*)d_in[7];
    const int*   b2revb  = (const int*)d_in[8];
    const int*   mol_ids = (const int*)d_in[9];

    const size_t sz_wih  = 320ull * 480 * 2;
    const size_t sz_wto  = 320ull * 448 * 2;
    const size_t sz_fbp  = 200000ull * 160 * 2;
    const size_t sz_amsg = 100000ull * 320 * 2;
    const size_t sz_msg  = 200000ull * 320 * 2;
    const size_t need = sz_wih + sz_wto + sz_fbp + sz_amsg + 2 * sz_msg;

    if (ws_size < need) {
        dbg_fill<<<(out_size + 255) / 256, 256, 0, stream>>>(
            (float*)d_out, out_size, (float)(ws_size >> 20));
        return;
    }

    char* ws = (char*)d_ws;
    unsigned short* wih  = (unsigned short*)(ws);
    unsigned short* wto  = (unsigned short*)(ws + sz_wih);
    unsigned short* fbp  = (unsigned short*)(ws + sz_wih + sz_wto);
    unsigned short* amsg = (unsigned short*)(ws + sz_wih + sz_wto + sz_fbp);
    unsigned short* msgA = (unsigned short*)(ws + sz_wih + sz_wto + sz_fbp + sz_amsg);
    unsigned short* msgB = (unsigned short*)(ws + sz_wih + sz_wto + sz_fbp + sz_amsg + sz_msg);
    unsigned short* concat = msgA;                     // msgA dead after loop
    float*          hid    = (float*)msgB;             // msgB dead after final gather

    prep_wih<<<600, 256, 0, stream>>>(W_i, W_h, wih);
    prep_wto<<<560, 256, 0, stream>>>(W_o, wto);
    pad_bonds<<<15625, 256, 0, stream>>>(f_bonds, fbp);

    // msgA = relu(f_bonds @ W_i)
    gemm_k<5, 0, 0, 480><<<dim3(1563, 2), 256, 0, stream>>>(
        fbp, 160, nullptr, nullptr, nullptr, nullptr, wih, msgA, nullptr, nullptr, 200000);

    unsigned short* cur = msgA;
    unsigned short* other = msgB;
    for (int d = 0; d < 3; ++d) {   // DEPTH-1
        gather_sum<40><<<15625, 256, 0, stream>>>(cur, a2b, amsg, 320, 100000);
        gemm_k<5, 10, 0, 480><<<dim3(1563, 2), 256, 0, stream>>>(
            fbp, 160, amsg, cur, b2a, b2revb, wih, other, nullptr, nullptr, 200000);
        unsigned short* t = cur; cur = other; other = t;
    }

    // final gather into concat cols 0..303 (cur == msgB; concat == msgA)
    gather_sum<38><<<14844, 256, 0, stream>>>(cur, a2b, concat, 448, 100000);
    atoms_concat<<<7032, 256, 0, stream>>>(f_atoms, concat);
    // hid = relu(concat @ W_o + b_o)
    gemm_k<14, 0, 2, 448><<<dim3(782, 2), 256, 0, stream>>>(
        concat, 448, nullptr, nullptr, nullptr, nullptr, wto, nullptr, hid, b_o, 100000);
    mean_k<<<8192, 320, 0, stream>>>(hid, mol_ids, (float*)d_out, 100000);
}